// Round 6
// baseline (214.339 us; speedup 1.0000x reference)
//
#include <hip/hip_runtime.h>
#include <math.h>

#define NB 4
#define NN 196
#define NC 64
#define ND0 800
#define NH 5
#define NO1 100
#define NC1 500   // heads*O1 = 5*100
#define NO2 64
#define TT 2      // targets per k_adj block
#define JC 4      // j-chunks per k_adj block
#define JW 200    // j per chunk (JC*JW == ND0)
#define TQ 4      // targets per k_gat1b block
#define OG 4      // o-groups per head in k_gat1a
#define OW 25     // o per group (OG*OW == NO1)
#define NEGF -1000000000.0f
#define TH_MARGIN 0.002f

// ---------------- K1: pl = transpose(latent) + positional encoding (f64 + f32 copies); zero fixup counter
__global__ void k_pl(const float* __restrict__ latent, double* __restrict__ pl_d, float* __restrict__ pl_f,
                     int* __restrict__ bcount) {
    int idx = blockIdx.x * blockDim.x + threadIdx.x;
    if (idx == 0) *bcount = 0;
    if (idx >= NB*NN*NC) return;
    int c = idx & (NC-1);
    int n = (idx >> 6) % NN;
    int b = idx / (NC*NN);
    int i = c >> 1;
    double div = exp((double)(2*i) * (-log(10000.0) / (double)NC));
    double ang = (double)n * div;
    double pe = (c & 1) ? cos(ang) : sin(ang);
    double v = (double)latent[(b*NC + c)*NN + n] + pe;
    pl_d[idx] = v;
    pl_f[idx] = (float)v;
}

// ---------------- K2: U[bn,j] = pl[n]·w1[:64,j] ; V[bn,j] = pl[n]·w1[64:,j] + b1[j]  (f64)
//                  also VT_f[b][j][s] f32 transposed copy of V for the f32 adj kernel
__global__ void k_uv(const double* __restrict__ pl_d, const float* __restrict__ w1,
                     const float* __restrict__ b1, double* __restrict__ U,
                     double* __restrict__ V, float* __restrict__ VT_f) {
    __shared__ double row[NC];
    int bn = blockIdx.x;           // b*NN+n
    int b = bn / NN, n = bn % NN;
    int tid = threadIdx.x;
    if (tid < NC) row[tid] = pl_d[bn*NC + tid];
    __syncthreads();
    for (int j = tid; j < ND0; j += blockDim.x) {
        double au = 0.0, av = (double)b1[j];
        #pragma unroll 8
        for (int k = 0; k < NC; ++k) {
            double p = row[k];
            au += p * (double)w1[k*ND0 + j];
            av += p * (double)w1[(NC + k)*ND0 + j];
        }
        U[(size_t)bn*ND0 + j] = au;
        V[(size_t)bn*ND0 + j] = av;
        VT_f[((size_t)b*ND0 + j)*NN + n] = (float)av;
    }
}

// ---------------- K3a: f32 adj MLP + gumbel margin -> WT + borderline list
__global__ void __launch_bounds__(1024)
k_adj32(const double* __restrict__ U, const float* __restrict__ VT,
        const float* __restrict__ w2, const float* __restrict__ b2,
        const float* __restrict__ gum, float* __restrict__ WT,
        int* __restrict__ blist, int* __restrict__ bcount) {
    __shared__ float Ul[TT][ND0];           // 6.4 KB
    __shared__ float w2l[ND0];              // 3.2 KB
    __shared__ float part[JC][TT][256];     // 8 KB
    int bi = blockIdx.x;
    int b = bi / (NN/TT);
    int t0 = (bi % (NN/TT)) * TT;
    int tid = threadIdx.x;
    int s = tid & 255;
    int chunk = tid >> 8;
    for (int idx = tid; idx < TT*ND0; idx += 1024) {
        int tt = idx / ND0, j = idx - tt*ND0;
        Ul[tt][j] = (float)U[((size_t)(b*NN + t0 + tt))*ND0 + j];
    }
    for (int j = tid; j < ND0; j += 1024) w2l[j] = w2[j];
    __syncthreads();
    float a0 = 0.0f, a1 = 0.0f;
    if (s < NN) {
        const float* vp = VT + ((size_t)b*ND0 + chunk*JW)*NN + s;
        int j0 = chunk*JW;
        #pragma unroll 4
        for (int jj = 0; jj < JW; ++jj) {
            float v = vp[(size_t)jj*NN];
            float w = w2l[j0 + jj];
            float h0 = Ul[0][j0 + jj] + v; h0 = (h0 >= 0.0f) ? h0 : 0.01f*h0; a0 = fmaf(h0, w, a0);
            float h1 = Ul[1][j0 + jj] + v; h1 = (h1 >= 0.0f) ? h1 : 0.01f*h1; a1 = fmaf(h1, w, a1);
        }
    }
    part[chunk][0][s] = a0;
    part[chunk][1][s] = a1;
    __syncthreads();
    if (tid < TT*NN) {
        int tt = tid / NN, ss = tid - tt*NN;
        float acc = b2[0] + part[0][tt][ss] + part[1][tt][ss]
                  + part[2][tt][ss] + part[3][tt][ss];
        int t = t0 + tt;
        float adj = 1.0f/(1.0f + expf(-acc));
        float l1 = logf(fmaxf(adj, 1e-4f));
        float l0 = logf(fmaxf(1.0f - adj, 1e-4f));
        float g0 = gum[((size_t)(b*NN + t)*NN + ss)*2 + 0];
        float g1 = gum[((size_t)(b*NN + t)*NN + ss)*2 + 1];
        float margin = (l1 + g1) - (l0 + g0);
        if (fabsf(margin) <= TH_MARGIN) {
            int li = atomicAdd(bcount, 1);
            blist[li] = (b*NN + t)*NN + ss;
        }
        WT[((size_t)(b*NN + ss))*NN + t] = (margin > 0.0f) ? adj : 0.0f;
    }
}

// ---------------- K3b: f64 exact recompute for borderline pairs (one pair per wave, wide grid)
__global__ void __launch_bounds__(256)
k_adjfix(const double* __restrict__ U, const double* __restrict__ V,
         const float* __restrict__ w2, const float* __restrict__ b2,
         const float* __restrict__ gum, const int* __restrict__ blist,
         const int* __restrict__ bcount, float* __restrict__ WT) {
    int nfix = *bcount;
    int gwid = (blockIdx.x * blockDim.x + threadIdx.x) >> 6;
    int lane = threadIdx.x & 63;
    int nw = (gridDim.x * blockDim.x) >> 6;
    for (int i = gwid; i < nfix; i += nw) {
        int code = blist[i];
        int s = code % NN;
        int t = (code / NN) % NN;
        int b = code / (NN*NN);
        const double* up = U + ((size_t)(b*NN + t))*ND0;
        const double* vp = V + ((size_t)(b*NN + s))*ND0;
        double a = 0.0;
        for (int j = lane; j < ND0; j += 64) {
            double h = up[j] + vp[j];
            h = (h >= 0.0) ? h : 0.01*h;
            a += h * (double)w2[j];
        }
        for (int off = 32; off >= 1; off >>= 1) a += __shfl_xor(a, off);
        if (lane == 0) {
            double acc = a + (double)b2[0];
            double adj = 1.0/(1.0 + exp(-acc));
            double l1 = log(fmax(adj, 1e-4));
            double l0 = log(fmax(1.0 - adj, 1e-4));
            double g0 = (double)gum[((size_t)(b*NN + t)*NN + s)*2 + 0];
            double g1 = (double)gum[((size_t)(b*NN + t)*NN + s)*2 + 1];
            double z0 = l0 + g0, z1 = l1 + g1;
            double m = fmax(z0, z1);
            double e0 = exp(z0 - m), e1 = exp(z1 - m);
            double sm = e0 + e1;
            int cg = (e1/sm) > (e0/sm);
            WT[((size_t)(b*NN + s))*NN + t] = cg ? (float)adj : 0.0f;
        }
    }
}

// ---------------- K4: GAT1 projections xl1/xl1T/xr1 = pl @ wl/wr + bl/br  (f32)
__global__ void k_proj1(const float* __restrict__ pl_f, const float* __restrict__ wl, const float* __restrict__ bl,
                        const float* __restrict__ wr, const float* __restrict__ br,
                        float* __restrict__ xl1, float* __restrict__ xl1T, float* __restrict__ xr1) {
    __shared__ float row[NC];
    int bn = blockIdx.x;
    int b = bn / NN, n = bn % NN;
    int tid = threadIdx.x;
    if (tid < NC) row[tid] = pl_f[bn*NC + tid];
    __syncthreads();
    for (int c = tid; c < NC1; c += blockDim.x) {
        float al = bl[c], ar = br[c];
        #pragma unroll 8
        for (int k = 0; k < NC; ++k) {
            float p = row[k];
            al += p * wl[k*NC1 + c];
            ar += p * wr[k*NC1 + c];
        }
        xl1[(size_t)bn*NC1 + c] = al;
        xr1[(size_t)bn*NC1 + c] = ar;
        xl1T[((size_t)b*NC1 + c)*256 + n] = al;
    }
}

// ---------------- K5a: GAT1 logits + softmax -> alphaG[b][h][t][s-pad256]
// 1024 threads = 256 s-lanes x 4 o-groups; shfl-based softmax on waves 0..3.
__global__ void __launch_bounds__(1024)
k_gat1a(const float* __restrict__ xl1T, const float* __restrict__ xr1,
        const float* __restrict__ WT, const float* __restrict__ we,
        const float* __restrict__ att, float* __restrict__ alphaG) {
    __shared__ float part[OG][NH][256];    // 20 KB
    __shared__ float wred[4][NH];
    __shared__ float mx[NH], sm[NH];
    __shared__ float wts_l[256];
    int blk = blockIdx.x;
    int b = blk / NN, t = blk % NN;
    int tid = threadIdx.x;
    int s = tid & 255;
    int g = tid >> 8;                       // 0..3
    if (tid < 256) wts_l[tid] = (tid < NN) ? WT[((size_t)(b*NN + t))*NN + tid] : 0.0f;
    __syncthreads();
    float wt = wts_l[s];
    const float* xT = xl1T + (size_t)b*NC1*256;
    const float* xr = xr1 + ((size_t)(b*NN + t))*NC1;
    #pragma unroll
    for (int h = 0; h < NH; ++h) {
        float a = 0.0f;
        int base = h*NO1 + g*OW;
        #pragma unroll
        for (int o = 0; o < OW; ++o) {
            int c = base + o;
            float x = xT[(size_t)c*256 + s];
            float v = fmaf(wt, we[c], x + xr[c]);
            float av = att[c];
            a += fmaxf(v, 0.0f)*av + fminf(v, 0.0f)*(0.2f*av);
        }
        part[g][h][s] = a;
    }
    __syncthreads();
    // waves 0..3 (tid<256, wave-uniform) finalize
    int lane = tid & 63, wid = tid >> 6;
    bool lead = (tid < 256);
    bool on = false;
    float accs[NH], es[NH];
    if (lead) {
        on = (s < NN) && (wt != 0.0f);
        #pragma unroll
        for (int h = 0; h < NH; ++h) {
            accs[h] = part[0][h][s] + part[1][h][s] + part[2][h][s] + part[3][h][s];
            float m = on ? accs[h] : NEGF;
            #pragma unroll
            for (int off = 32; off >= 1; off >>= 1) m = fmaxf(m, __shfl_xor(m, off));
            if (lane == 0) wred[wid][h] = m;
        }
    }
    __syncthreads();
    if (tid < NH) mx[tid] = fmaxf(fmaxf(wred[0][tid], wred[1][tid]), fmaxf(wred[2][tid], wred[3][tid]));
    __syncthreads();
    if (lead) {
        #pragma unroll
        for (int h = 0; h < NH; ++h) {
            float e = on ? expf(accs[h] - mx[h]) : 0.0f;
            es[h] = e;
            float r = e;
            #pragma unroll
            for (int off = 32; off >= 1; off >>= 1) r += __shfl_xor(r, off);
            if (lane == 0) wred[wid][h] = r;
        }
    }
    __syncthreads();
    if (tid < NH) sm[tid] = wred[0][tid] + wred[1][tid] + wred[2][tid] + wred[3][tid];
    __syncthreads();
    if (lead) {
        #pragma unroll
        for (int h = 0; h < NH; ++h) {
            float a = (sm[h] > 0.0f) ? es[h] / sm[h] : 0.0f;
            alphaG[(((size_t)b*NH + h)*NN + t)*256 + s] = a;
        }
    }
}

// ---------------- K5b: GAT1 aggregate
__global__ void __launch_bounds__(640)
k_gat1b(const float* __restrict__ xl1, const float* __restrict__ alphaG,
        const float* __restrict__ bias, float* __restrict__ x1) {
    int blk = blockIdx.x;
    int b = blk / (NN/TQ), tq = blk % (NN/TQ);
    int tid = threadIdx.x;
    int w = tid >> 6, l = tid & 63;
    int h = w >> 1, csub = w & 1;
    int o = csub*64 + l;
    bool active = (o < NO1);
    int c = h*NO1 + (active ? o : 0);
    const float* ap = alphaG + (((size_t)b*NH + h)*NN + tq*TQ)*256;
    const float* xp = xl1 + (size_t)b*NN*NC1 + c;
    float a0 = 0.f, a1 = 0.f, a2 = 0.f, a3 = 0.f;
    for (int s = 0; s < NN; ++s) {
        float x = xp[(size_t)s*NC1];
        float p0 = ap[s], p1 = ap[256 + s], p2 = ap[512 + s], p3 = ap[768 + s];
        a0 = fmaf(p0, x, a0); a1 = fmaf(p1, x, a1);
        a2 = fmaf(p2, x, a2); a3 = fmaf(p3, x, a3);
    }
    if (active) {
        float bs = bias[c];
        float v;
        v = a0 + bs; x1[((size_t)(b*NN + tq*TQ + 0))*NC1 + c] = (v >= 0.f) ? v : 0.01f*v;
        v = a1 + bs; x1[((size_t)(b*NN + tq*TQ + 1))*NC1 + c] = (v >= 0.f) ? v : 0.01f*v;
        v = a2 + bs; x1[((size_t)(b*NN + tq*TQ + 2))*NC1 + c] = (v >= 0.f) ? v : 0.01f*v;
        v = a3 + bs; x1[((size_t)(b*NN + tq*TQ + 3))*NC1 + c] = (v >= 0.f) ? v : 0.01f*v;
    }
}

// ---------------- K6: GAT2 head-0 projections
__global__ void k_proj2(const float* __restrict__ x1, const float* __restrict__ wl, const float* __restrict__ bl,
                        const float* __restrict__ wr, const float* __restrict__ br,
                        float* __restrict__ xl2, float* __restrict__ xl2T, float* __restrict__ xr2) {
    __shared__ float row[NC1];
    __shared__ float part[256];
    int bn = blockIdx.x;
    int b = bn / NN, n = bn % NN;
    int tid = threadIdx.x;
    for (int c = tid; c < NC1; c += 256) row[c] = x1[(size_t)bn*NC1 + c];
    __syncthreads();
    int which = tid >> 7;
    int o = tid & 63;
    int half = (tid >> 6) & 1;
    const float* w = which ? wr : wl;
    float acc = 0.0f;
    for (int k = half*250; k < half*250 + 250; ++k)
        acc += row[k] * w[(size_t)k*320 + o];
    part[tid] = acc;
    __syncthreads();
    if ((tid & 64) == 0) {
        float tot = part[tid] + part[tid + 64];
        if (which == 0) {
            float v = tot + bl[o];
            xl2[(size_t)bn*NO2 + o] = v;
            xl2T[((size_t)b*NO2 + o)*256 + n] = v;
        } else {
            xr2[(size_t)bn*NO2 + o] = tot + br[o];
        }
    }
}

// ---------------- K7: GAT2 head-0 attention + final channel softmax -> out
__global__ void __launch_bounds__(256)
k_gat2(const float* __restrict__ xl2T, const float* __restrict__ xl2,
       const float* __restrict__ xr2, const float* __restrict__ WT,
       const float* __restrict__ we, const float* __restrict__ att,
       const float* __restrict__ bias, float* __restrict__ out) {
    __shared__ float red[256], alpha_l[256], part[4][NO2];
    __shared__ float mxs, sms;
    int blk = blockIdx.x;
    int b = blk / NN, t = blk % NN;
    int s = threadIdx.x;
    float wt = (s < NN) ? WT[((size_t)(b*NN + t))*NN + s] : 0.0f;
    const float* xT = xl2T + (size_t)b*NO2*256;
    const float* xr = xr2 + ((size_t)(b*NN + t))*NO2;
    float acc = 0.0f;
    for (int c = 0; c < NO2; ++c) {
        float x = xT[(size_t)c*256 + s];
        float v = fmaf(wt, we[c], x + xr[c]);
        float av = att[c];
        acc += fmaxf(v, 0.0f)*av + fminf(v, 0.0f)*(0.2f*av);
    }
    bool on = (s < NN) && (wt != 0.0f);
    float lgt = on ? acc : NEGF;
    red[s] = lgt;
    __syncthreads();
    for (int d = 128; d >= 1; d >>= 1) {
        if (s < d) red[s] = fmaxf(red[s], red[s + d]);
        __syncthreads();
    }
    if (s == 0) mxs = red[0];
    __syncthreads();
    float e = on ? expf(acc - mxs) : 0.0f;
    red[s] = e;
    __syncthreads();
    for (int d = 128; d >= 1; d >>= 1) {
        if (s < d) red[s] += red[s + d];
        __syncthreads();
    }
    if (s == 0) sms = red[0];
    __syncthreads();
    alpha_l[s] = (sms > 0.0f) ? e / sms : 0.0f;
    __syncthreads();
    int c = s & 63, sq = s >> 6;
    float pa = 0.0f;
    const float* xp = xl2 + (size_t)b*NN*NO2 + c;
    for (int ss = sq*49; ss < sq*49 + 49; ++ss)
        pa = fmaf(alpha_l[ss], xp[(size_t)ss*NO2], pa);
    part[sq][c] = pa;
    __syncthreads();
    if (s < NO2) {
        float ny = part[0][s] + part[1][s] + part[2][s] + part[3][s] + bias[s];
        float m = ny;
        for (int off = 32; off >= 1; off >>= 1) m = fmaxf(m, __shfl_xor(m, off));
        float ee = expf(ny - m);
        float ssum = ee;
        for (int off = 32; off >= 1; off >>= 1) ssum += __shfl_xor(ssum, off);
        out[((size_t)(b*NN + t))*NO2 + s] = ee / ssum;
    }
}

extern "C" void kernel_launch(void* const* d_in, const int* in_sizes, int n_in,
                              void* d_out, int out_size, void* d_ws, size_t ws_size,
                              hipStream_t stream) {
    const float* latent  = (const float*)d_in[0];
    const float* gum     = (const float*)d_in[1];
    const float* d0_w1   = (const float*)d_in[2];
    const float* d0_b1   = (const float*)d_in[3];
    const float* d0_w2   = (const float*)d_in[4];
    const float* d0_b2   = (const float*)d_in[5];
    const float* g1_wl   = (const float*)d_in[12];
    const float* g1_bl   = (const float*)d_in[13];
    const float* g1_wr   = (const float*)d_in[14];
    const float* g1_br   = (const float*)d_in[15];
    const float* g1_we   = (const float*)d_in[16];
    const float* g1_att  = (const float*)d_in[17];
    const float* g1_bias = (const float*)d_in[18];
    const float* g2_wl   = (const float*)d_in[19];
    const float* g2_bl   = (const float*)d_in[20];
    const float* g2_wr   = (const float*)d_in[21];
    const float* g2_br   = (const float*)d_in[22];
    const float* g2_we   = (const float*)d_in[23];
    const float* g2_att  = (const float*)d_in[24];
    const float* g2_bias = (const float*)d_in[25];
    float* out = (float*)d_out;

    char* ws = (char*)d_ws;
    size_t off = 0;
    auto alloc = [&](size_t bytes) { char* p = ws + off; off += (bytes + 255) & ~(size_t)255; return (void*)p; };
    double* pl_d  = (double*)alloc((size_t)NB*NN*NC*8);
    float*  pl_f  = (float*) alloc((size_t)NB*NN*NC*4);
    double* U_d   = (double*)alloc((size_t)NB*NN*ND0*8);
    double* V_d   = (double*)alloc((size_t)NB*NN*ND0*8);
    float*  VT_f  = (float*) alloc((size_t)NB*ND0*NN*4);
    float*  WT    = (float*) alloc((size_t)NB*NN*NN*4);
    float*  xl1   = (float*) alloc((size_t)NB*NN*NC1*4);
    float*  xl1T  = (float*) alloc((size_t)NB*NC1*256*4);
    float*  xr1   = (float*) alloc((size_t)NB*NN*NC1*4);
    float*  alphaG= (float*) alloc((size_t)NB*NH*NN*256*4);
    float*  x1    = (float*) alloc((size_t)NB*NN*NC1*4);
    float*  xl2   = (float*) alloc((size_t)NB*NN*NO2*4);
    float*  xl2T  = (float*) alloc((size_t)NB*NO2*256*4);
    float*  xr2   = (float*) alloc((size_t)NB*NN*NO2*4);
    int*    blist = (int*)   alloc((size_t)NB*NN*NN*4);
    int*    bcount= (int*)   alloc(256);

    hipLaunchKernelGGL(k_pl,     dim3((NB*NN*NC + 255)/256), dim3(256), 0, stream, latent, pl_d, pl_f, bcount);
    hipLaunchKernelGGL(k_uv,     dim3(NB*NN),       dim3(256),  0, stream, pl_d, d0_w1, d0_b1, U_d, V_d, VT_f);
    hipLaunchKernelGGL(k_adj32,  dim3(NB*(NN/TT)),  dim3(1024), 0, stream, U_d, VT_f, d0_w2, d0_b2, gum, WT, blist, bcount);
    hipLaunchKernelGGL(k_adjfix, dim3(256),         dim3(256),  0, stream, U_d, V_d, d0_w2, d0_b2, gum, blist, bcount, WT);
    hipLaunchKernelGGL(k_proj1,  dim3(NB*NN),       dim3(256),  0, stream, pl_f, g1_wl, g1_bl, g1_wr, g1_br, xl1, xl1T, xr1);
    hipLaunchKernelGGL(k_gat1a,  dim3(NB*NN),       dim3(1024), 0, stream, xl1T, xr1, WT, g1_we, g1_att, alphaG);
    hipLaunchKernelGGL(k_gat1b,  dim3(NB*(NN/TQ)),  dim3(640),  0, stream, xl1, alphaG, g1_bias, x1);
    hipLaunchKernelGGL(k_proj2,  dim3(NB*NN),       dim3(256),  0, stream, x1, g2_wl, g2_bl, g2_wr, g2_br, xl2, xl2T, xr2);
    hipLaunchKernelGGL(k_gat2,   dim3(NB*NN),       dim3(256),  0, stream, xl2T, xl2, xr2, WT, g2_we, g2_att, g2_bias, out);
}

// Round 7
// 166.447 us; speedup vs baseline: 1.2877x; 1.2877x over previous
//
#include <hip/hip_runtime.h>
#include <math.h>

#define NB 4
#define NN 196
#define NC 64
#define ND0 800
#define NH 5
#define NO1 100
#define NC1 500   // heads*O1 = 5*100
#define NO2 64
#define TT 2      // targets per k_adj block
#define JC 4      // j-chunks per k_adj block
#define JW 200    // j per chunk (JC*JW == ND0)
#define TQ 4      // targets per k_gat1b block
#define NEGF -1000000000.0f
#define TH_MARGIN 0.002f

// ---------------- K1: pl = transpose(latent) + positional encoding (f64 + f32 copies); zero fixup counter
__global__ void k_pl(const float* __restrict__ latent, double* __restrict__ pl_d, float* __restrict__ pl_f,
                     int* __restrict__ bcount) {
    int idx = blockIdx.x * blockDim.x + threadIdx.x;
    if (idx == 0) *bcount = 0;
    if (idx >= NB*NN*NC) return;
    int c = idx & (NC-1);
    int n = (idx >> 6) % NN;
    int b = idx / (NC*NN);
    int i = c >> 1;
    double div = exp((double)(2*i) * (-log(10000.0) / (double)NC));
    double ang = (double)n * div;
    double pe = (c & 1) ? cos(ang) : sin(ang);
    double v = (double)latent[(b*NC + c)*NN + n] + pe;
    pl_d[idx] = v;
    pl_f[idx] = (float)v;
}

// ---------------- K2: U[bn,j] = pl[n]·w1[:64,j] ; V[bn,j] = pl[n]·w1[64:,j] + b1[j]  (f64)
//                  also VT_f[b][j][s] f32 transposed copy of V for the f32 adj kernel
__global__ void k_uv(const double* __restrict__ pl_d, const float* __restrict__ w1,
                     const float* __restrict__ b1, double* __restrict__ U,
                     double* __restrict__ V, float* __restrict__ VT_f) {
    __shared__ double row[NC];
    int bn = blockIdx.x;           // b*NN+n
    int b = bn / NN, n = bn % NN;
    int tid = threadIdx.x;
    if (tid < NC) row[tid] = pl_d[bn*NC + tid];
    __syncthreads();
    for (int j = tid; j < ND0; j += blockDim.x) {
        double au = 0.0, av = (double)b1[j];
        #pragma unroll 8
        for (int k = 0; k < NC; ++k) {
            double p = row[k];
            au += p * (double)w1[k*ND0 + j];
            av += p * (double)w1[(NC + k)*ND0 + j];
        }
        U[(size_t)bn*ND0 + j] = au;
        V[(size_t)bn*ND0 + j] = av;
        VT_f[((size_t)b*ND0 + j)*NN + n] = (float)av;
    }
}

// ---------------- K3a: f32 adj MLP + gumbel margin -> WT + borderline list
__global__ void __launch_bounds__(1024)
k_adj32(const double* __restrict__ U, const float* __restrict__ VT,
        const float* __restrict__ w2, const float* __restrict__ b2,
        const float* __restrict__ gum, float* __restrict__ WT,
        int* __restrict__ blist, int* __restrict__ bcount) {
    __shared__ float Ul[TT][ND0];           // 6.4 KB
    __shared__ float w2l[ND0];              // 3.2 KB
    __shared__ float part[JC][TT][256];     // 8 KB
    int bi = blockIdx.x;
    int b = bi / (NN/TT);
    int t0 = (bi % (NN/TT)) * TT;
    int tid = threadIdx.x;
    int s = tid & 255;
    int chunk = tid >> 8;
    for (int idx = tid; idx < TT*ND0; idx += 1024) {
        int tt = idx / ND0, j = idx - tt*ND0;
        Ul[tt][j] = (float)U[((size_t)(b*NN + t0 + tt))*ND0 + j];
    }
    for (int j = tid; j < ND0; j += 1024) w2l[j] = w2[j];
    __syncthreads();
    float a0 = 0.0f, a1 = 0.0f;
    if (s < NN) {
        const float* vp = VT + ((size_t)b*ND0 + chunk*JW)*NN + s;
        int j0 = chunk*JW;
        #pragma unroll 4
        for (int jj = 0; jj < JW; ++jj) {
            float v = vp[(size_t)jj*NN];
            float w = w2l[j0 + jj];
            float h0 = Ul[0][j0 + jj] + v; h0 = (h0 >= 0.0f) ? h0 : 0.01f*h0; a0 = fmaf(h0, w, a0);
            float h1 = Ul[1][j0 + jj] + v; h1 = (h1 >= 0.0f) ? h1 : 0.01f*h1; a1 = fmaf(h1, w, a1);
        }
    }
    part[chunk][0][s] = a0;
    part[chunk][1][s] = a1;
    __syncthreads();
    if (tid < TT*NN) {
        int tt = tid / NN, ss = tid - tt*NN;
        float acc = b2[0] + part[0][tt][ss] + part[1][tt][ss]
                  + part[2][tt][ss] + part[3][tt][ss];
        int t = t0 + tt;
        float adj = 1.0f/(1.0f + expf(-acc));
        float l1 = logf(fmaxf(adj, 1e-4f));
        float l0 = logf(fmaxf(1.0f - adj, 1e-4f));
        float g0 = gum[((size_t)(b*NN + t)*NN + ss)*2 + 0];
        float g1 = gum[((size_t)(b*NN + t)*NN + ss)*2 + 1];
        float margin = (l1 + g1) - (l0 + g0);
        if (fabsf(margin) <= TH_MARGIN) {
            int li = atomicAdd(bcount, 1);
            blist[li] = (b*NN + t)*NN + ss;
        }
        WT[((size_t)(b*NN + ss))*NN + t] = (margin > 0.0f) ? adj : 0.0f;
    }
}

// ---------------- K3b: f64 exact recompute for borderline pairs (one pair per wave, wide grid)
__global__ void __launch_bounds__(256)
k_adjfix(const double* __restrict__ U, const double* __restrict__ V,
         const float* __restrict__ w2, const float* __restrict__ b2,
         const float* __restrict__ gum, const int* __restrict__ blist,
         const int* __restrict__ bcount, float* __restrict__ WT) {
    int nfix = *bcount;
    int gwid = (blockIdx.x * blockDim.x + threadIdx.x) >> 6;
    int lane = threadIdx.x & 63;
    int nw = (gridDim.x * blockDim.x) >> 6;
    for (int i = gwid; i < nfix; i += nw) {
        int code = blist[i];
        int s = code % NN;
        int t = (code / NN) % NN;
        int b = code / (NN*NN);
        const double* up = U + ((size_t)(b*NN + t))*ND0;
        const double* vp = V + ((size_t)(b*NN + s))*ND0;
        double a = 0.0;
        for (int j = lane; j < ND0; j += 64) {
            double h = up[j] + vp[j];
            h = (h >= 0.0) ? h : 0.01*h;
            a += h * (double)w2[j];
        }
        for (int off = 32; off >= 1; off >>= 1) a += __shfl_xor(a, off);
        if (lane == 0) {
            double acc = a + (double)b2[0];
            double adj = 1.0/(1.0 + exp(-acc));
            double l1 = log(fmax(adj, 1e-4));
            double l0 = log(fmax(1.0 - adj, 1e-4));
            double g0 = (double)gum[((size_t)(b*NN + t)*NN + s)*2 + 0];
            double g1 = (double)gum[((size_t)(b*NN + t)*NN + s)*2 + 1];
            double z0 = l0 + g0, z1 = l1 + g1;
            double m = fmax(z0, z1);
            double e0 = exp(z0 - m), e1 = exp(z1 - m);
            double sm = e0 + e1;
            int cg = (e1/sm) > (e0/sm);
            WT[((size_t)(b*NN + s))*NN + t] = cg ? (float)adj : 0.0f;
        }
    }
}

// ---------------- K4: GAT1 projections xl1/xl1T/xr1 = pl @ wl/wr + bl/br  (f32)
__global__ void k_proj1(const float* __restrict__ pl_f, const float* __restrict__ wl, const float* __restrict__ bl,
                        const float* __restrict__ wr, const float* __restrict__ br,
                        float* __restrict__ xl1, float* __restrict__ xl1T, float* __restrict__ xr1) {
    __shared__ float row[NC];
    int bn = blockIdx.x;
    int b = bn / NN, n = bn % NN;
    int tid = threadIdx.x;
    if (tid < NC) row[tid] = pl_f[bn*NC + tid];
    __syncthreads();
    for (int c = tid; c < NC1; c += blockDim.x) {
        float al = bl[c], ar = br[c];
        #pragma unroll 8
        for (int k = 0; k < NC; ++k) {
            float p = row[k];
            al += p * wl[k*NC1 + c];
            ar += p * wr[k*NC1 + c];
        }
        xl1[(size_t)bn*NC1 + c] = al;
        xr1[(size_t)bn*NC1 + c] = ar;
        xl1T[((size_t)b*NC1 + c)*256 + n] = al;
    }
}

// ---------------- K5a: GAT1 logits + softmax -> alphaG[(b*NH+h)*NN+t][s]
// One block per (b, h, t): 256 threads = s-lanes; 100-iter chain; shfl softmax.
__global__ void __launch_bounds__(256)
k_gat1a(const float* __restrict__ xl1T, const float* __restrict__ xr1,
        const float* __restrict__ WT, const float* __restrict__ we,
        const float* __restrict__ att, float* __restrict__ alphaG) {
    __shared__ float wred[4];
    __shared__ float mxs, sms;
    int blk = blockIdx.x;          // (b*NH + h)*NN + t
    int t = blk % NN;
    int bh = blk / NN;
    int h = bh % NH;
    int b = bh / NH;
    int s = threadIdx.x;
    int lane = s & 63, wid = s >> 6;
    float wt = (s < NN) ? WT[((size_t)(b*NN + t))*NN + s] : 0.0f;
    const float* xT  = xl1T + ((size_t)b*NC1 + h*NO1)*256;
    const float* xr  = xr1 + ((size_t)(b*NN + t))*NC1 + h*NO1;
    const float* weh = we + h*NO1;
    const float* ath = att + h*NO1;
    float a = 0.0f;
    #pragma unroll 5
    for (int o = 0; o < NO1; ++o) {
        float x = xT[(size_t)o*256 + s];
        float v = fmaf(wt, weh[o], x + xr[o]);
        float av = ath[o];
        a += fmaxf(v, 0.0f)*av + fminf(v, 0.0f)*(0.2f*av);
    }
    bool on = (s < NN) && (wt != 0.0f);
    float m = on ? a : NEGF;
    #pragma unroll
    for (int off = 32; off >= 1; off >>= 1) m = fmaxf(m, __shfl_xor(m, off));
    if (lane == 0) wred[wid] = m;
    __syncthreads();
    if (s == 0) mxs = fmaxf(fmaxf(wred[0], wred[1]), fmaxf(wred[2], wred[3]));
    __syncthreads();
    float e = on ? expf(a - mxs) : 0.0f;
    float r = e;
    #pragma unroll
    for (int off = 32; off >= 1; off >>= 1) r += __shfl_xor(r, off);
    if (lane == 0) wred[wid] = r;
    __syncthreads();
    if (s == 0) sms = wred[0] + wred[1] + wred[2] + wred[3];
    __syncthreads();
    alphaG[(size_t)blk*256 + s] = (sms > 0.0f) ? e / sms : 0.0f;
}

// ---------------- K5b: GAT1 aggregate
__global__ void __launch_bounds__(640)
k_gat1b(const float* __restrict__ xl1, const float* __restrict__ alphaG,
        const float* __restrict__ bias, float* __restrict__ x1) {
    int blk = blockIdx.x;
    int b = blk / (NN/TQ), tq = blk % (NN/TQ);
    int tid = threadIdx.x;
    int w = tid >> 6, l = tid & 63;
    int h = w >> 1, csub = w & 1;
    int o = csub*64 + l;
    bool active = (o < NO1);
    int c = h*NO1 + (active ? o : 0);
    const float* ap = alphaG + (((size_t)b*NH + h)*NN + tq*TQ)*256;
    const float* xp = xl1 + (size_t)b*NN*NC1 + c;
    float a0 = 0.f, a1 = 0.f, a2 = 0.f, a3 = 0.f;
    for (int s = 0; s < NN; ++s) {
        float x = xp[(size_t)s*NC1];
        float p0 = ap[s], p1 = ap[256 + s], p2 = ap[512 + s], p3 = ap[768 + s];
        a0 = fmaf(p0, x, a0); a1 = fmaf(p1, x, a1);
        a2 = fmaf(p2, x, a2); a3 = fmaf(p3, x, a3);
    }
    if (active) {
        float bs = bias[c];
        float v;
        v = a0 + bs; x1[((size_t)(b*NN + tq*TQ + 0))*NC1 + c] = (v >= 0.f) ? v : 0.01f*v;
        v = a1 + bs; x1[((size_t)(b*NN + tq*TQ + 1))*NC1 + c] = (v >= 0.f) ? v : 0.01f*v;
        v = a2 + bs; x1[((size_t)(b*NN + tq*TQ + 2))*NC1 + c] = (v >= 0.f) ? v : 0.01f*v;
        v = a3 + bs; x1[((size_t)(b*NN + tq*TQ + 3))*NC1 + c] = (v >= 0.f) ? v : 0.01f*v;
    }
}

// ---------------- K6: GAT2 head-0 projections
__global__ void k_proj2(const float* __restrict__ x1, const float* __restrict__ wl, const float* __restrict__ bl,
                        const float* __restrict__ wr, const float* __restrict__ br,
                        float* __restrict__ xl2, float* __restrict__ xl2T, float* __restrict__ xr2) {
    __shared__ float row[NC1];
    __shared__ float part[256];
    int bn = blockIdx.x;
    int b = bn / NN, n = bn % NN;
    int tid = threadIdx.x;
    for (int c = tid; c < NC1; c += 256) row[c] = x1[(size_t)bn*NC1 + c];
    __syncthreads();
    int which = tid >> 7;
    int o = tid & 63;
    int half = (tid >> 6) & 1;
    const float* w = which ? wr : wl;
    float acc = 0.0f;
    for (int k = half*250; k < half*250 + 250; ++k)
        acc += row[k] * w[(size_t)k*320 + o];
    part[tid] = acc;
    __syncthreads();
    if ((tid & 64) == 0) {
        float tot = part[tid] + part[tid + 64];
        if (which == 0) {
            float v = tot + bl[o];
            xl2[(size_t)bn*NO2 + o] = v;
            xl2T[((size_t)b*NO2 + o)*256 + n] = v;
        } else {
            xr2[(size_t)bn*NO2 + o] = tot + br[o];
        }
    }
}

// ---------------- K7: GAT2 head-0 attention + final channel softmax -> out
__global__ void __launch_bounds__(256)
k_gat2(const float* __restrict__ xl2T, const float* __restrict__ xl2,
       const float* __restrict__ xr2, const float* __restrict__ WT,
       const float* __restrict__ we, const float* __restrict__ att,
       const float* __restrict__ bias, float* __restrict__ out) {
    __shared__ float red[256], alpha_l[256], part[4][NO2];
    __shared__ float mxs, sms;
    int blk = blockIdx.x;
    int b = blk / NN, t = blk % NN;
    int s = threadIdx.x;
    float wt = (s < NN) ? WT[((size_t)(b*NN + t))*NN + s] : 0.0f;
    const float* xT = xl2T + (size_t)b*NO2*256;
    const float* xr = xr2 + ((size_t)(b*NN + t))*NO2;
    float acc = 0.0f;
    for (int c = 0; c < NO2; ++c) {
        float x = xT[(size_t)c*256 + s];
        float v = fmaf(wt, we[c], x + xr[c]);
        float av = att[c];
        acc += fmaxf(v, 0.0f)*av + fminf(v, 0.0f)*(0.2f*av);
    }
    bool on = (s < NN) && (wt != 0.0f);
    float lgt = on ? acc : NEGF;
    red[s] = lgt;
    __syncthreads();
    for (int d = 128; d >= 1; d >>= 1) {
        if (s < d) red[s] = fmaxf(red[s], red[s + d]);
        __syncthreads();
    }
    if (s == 0) mxs = red[0];
    __syncthreads();
    float e = on ? expf(acc - mxs) : 0.0f;
    red[s] = e;
    __syncthreads();
    for (int d = 128; d >= 1; d >>= 1) {
        if (s < d) red[s] += red[s + d];
        __syncthreads();
    }
    if (s == 0) sms = red[0];
    __syncthreads();
    alpha_l[s] = (sms > 0.0f) ? e / sms : 0.0f;
    __syncthreads();
    int c = s & 63, sq = s >> 6;
    float pa = 0.0f;
    const float* xp = xl2 + (size_t)b*NN*NO2 + c;
    for (int ss = sq*49; ss < sq*49 + 49; ++ss)
        pa = fmaf(alpha_l[ss], xp[(size_t)ss*NO2], pa);
    part[sq][c] = pa;
    __syncthreads();
    if (s < NO2) {
        float ny = part[0][s] + part[1][s] + part[2][s] + part[3][s] + bias[s];
        float m = ny;
        for (int off = 32; off >= 1; off >>= 1) m = fmaxf(m, __shfl_xor(m, off));
        float ee = expf(ny - m);
        float ssum = ee;
        for (int off = 32; off >= 1; off >>= 1) ssum += __shfl_xor(ssum, off);
        out[((size_t)(b*NN + t))*NO2 + s] = ee / ssum;
    }
}

extern "C" void kernel_launch(void* const* d_in, const int* in_sizes, int n_in,
                              void* d_out, int out_size, void* d_ws, size_t ws_size,
                              hipStream_t stream) {
    const float* latent  = (const float*)d_in[0];
    const float* gum     = (const float*)d_in[1];
    const float* d0_w1   = (const float*)d_in[2];
    const float* d0_b1   = (const float*)d_in[3];
    const float* d0_w2   = (const float*)d_in[4];
    const float* d0_b2   = (const float*)d_in[5];
    const float* g1_wl   = (const float*)d_in[12];
    const float* g1_bl   = (const float*)d_in[13];
    const float* g1_wr   = (const float*)d_in[14];
    const float* g1_br   = (const float*)d_in[15];
    const float* g1_we   = (const float*)d_in[16];
    const float* g1_att  = (const float*)d_in[17];
    const float* g1_bias = (const float*)d_in[18];
    const float* g2_wl   = (const float*)d_in[19];
    const float* g2_bl   = (const float*)d_in[20];
    const float* g2_wr   = (const float*)d_in[21];
    const float* g2_br   = (const float*)d_in[22];
    const float* g2_we   = (const float*)d_in[23];
    const float* g2_att  = (const float*)d_in[24];
    const float* g2_bias = (const float*)d_in[25];
    float* out = (float*)d_out;

    char* ws = (char*)d_ws;
    size_t off = 0;
    auto alloc = [&](size_t bytes) { char* p = ws + off; off += (bytes + 255) & ~(size_t)255; return (void*)p; };
    double* pl_d  = (double*)alloc((size_t)NB*NN*NC*8);
    float*  pl_f  = (float*) alloc((size_t)NB*NN*NC*4);
    double* U_d   = (double*)alloc((size_t)NB*NN*ND0*8);
    double* V_d   = (double*)alloc((size_t)NB*NN*ND0*8);
    float*  VT_f  = (float*) alloc((size_t)NB*ND0*NN*4);
    float*  WT    = (float*) alloc((size_t)NB*NN*NN*4);
    float*  xl1   = (float*) alloc((size_t)NB*NN*NC1*4);
    float*  xl1T  = (float*) alloc((size_t)NB*NC1*256*4);
    float*  xr1   = (float*) alloc((size_t)NB*NN*NC1*4);
    float*  alphaG= (float*) alloc((size_t)NB*NH*NN*256*4);
    float*  x1    = (float*) alloc((size_t)NB*NN*NC1*4);
    float*  xl2   = (float*) alloc((size_t)NB*NN*NO2*4);
    float*  xl2T  = (float*) alloc((size_t)NB*NO2*256*4);
    float*  xr2   = (float*) alloc((size_t)NB*NN*NO2*4);
    int*    blist = (int*)   alloc((size_t)NB*NN*NN*4);
    int*    bcount= (int*)   alloc(256);

    hipLaunchKernelGGL(k_pl,     dim3((NB*NN*NC + 255)/256), dim3(256), 0, stream, latent, pl_d, pl_f, bcount);
    hipLaunchKernelGGL(k_uv,     dim3(NB*NN),       dim3(256),  0, stream, pl_d, d0_w1, d0_b1, U_d, V_d, VT_f);
    hipLaunchKernelGGL(k_adj32,  dim3(NB*(NN/TT)),  dim3(1024), 0, stream, U_d, VT_f, d0_w2, d0_b2, gum, WT, blist, bcount);
    hipLaunchKernelGGL(k_adjfix, dim3(256),         dim3(256),  0, stream, U_d, V_d, d0_w2, d0_b2, gum, blist, bcount, WT);
    hipLaunchKernelGGL(k_proj1,  dim3(NB*NN),       dim3(256),  0, stream, pl_f, g1_wl, g1_bl, g1_wr, g1_br, xl1, xl1T, xr1);
    hipLaunchKernelGGL(k_gat1a,  dim3(NB*NH*NN),    dim3(256),  0, stream, xl1T, xr1, WT, g1_we, g1_att, alphaG);
    hipLaunchKernelGGL(k_gat1b,  dim3(NB*(NN/TQ)),  dim3(640),  0, stream, xl1, alphaG, g1_bias, x1);
    hipLaunchKernelGGL(k_proj2,  dim3(NB*NN),       dim3(256),  0, stream, x1, g2_wl, g2_bl, g2_wr, g2_br, xl2, xl2T, xr2);
    hipLaunchKernelGGL(k_gat2,   dim3(NB*NN),       dim3(256),  0, stream, xl2T, xl2, xr2, WT, g2_we, g2_att, g2_bias, out);
}

// Round 8
// 159.464 us; speedup vs baseline: 1.3441x; 1.0438x over previous
//
#include <hip/hip_runtime.h>
#include <math.h>

#define NB 4
#define NN 196
#define NC 64
#define ND0 800
#define NH 5
#define NO1 100
#define NC1 500   // heads*O1 = 5*100
#define NO2 64
#define TT 2      // targets per k_adj block
#define JC 4      // j-chunks per k_adj block
#define JW 200    // j per chunk (JC*JW == ND0)
#define TQ 2      // targets per k_gat1b block
#define NEGF -1000000000.0f
#define TH_MARGIN 0.002f

// ---------------- K1 (fused): uv role (392 blocks, 2 rows each) + proj1 role (784 blocks)
// PE computed inline in f64 (identical formula to reference path).
__global__ void __launch_bounds__(256)
k_head(const float* __restrict__ latent,
       const float* __restrict__ w1, const float* __restrict__ b1,
       const float* __restrict__ wl, const float* __restrict__ bl,
       const float* __restrict__ wr, const float* __restrict__ br,
       double* __restrict__ U, double* __restrict__ V, float* __restrict__ VT_f,
       float* __restrict__ xl1, float* __restrict__ xl1T, float* __restrict__ xr1,
       int* __restrict__ bcount) {
    __shared__ double rowd[2][NC];
    __shared__ float  rowf[NC];
    int bi = blockIdx.x;
    int tid = threadIdx.x;
    if (bi == 0 && tid == 0) *bcount = 0;
    if (bi < NB*(NN/2)) {
        // ---- uv role: rows n0, n0+1 of batch b ----
        int b = bi / (NN/2);
        int n0 = (bi % (NN/2)) * 2;
        if (tid < 128) {
            int r = tid >> 6, c = tid & 63;
            int n = n0 + r;
            double div = exp((double)(2*(c >> 1)) * (-log(10000.0) / (double)NC));
            double ang = (double)n * div;
            double pe = (c & 1) ? cos(ang) : sin(ang);
            rowd[r][c] = (double)latent[(b*NC + c)*NN + n] + pe;
        }
        __syncthreads();
        size_t bn0 = (size_t)(b*NN + n0);
        for (int j = tid; j < ND0; j += 256) {
            double au0 = 0.0, au1 = 0.0;
            double av0 = (double)b1[j], av1 = av0;
            #pragma unroll 8
            for (int k = 0; k < NC; ++k) {
                double p0 = rowd[0][k], p1 = rowd[1][k];
                double wu = (double)w1[k*ND0 + j];
                double wv = (double)w1[(NC + k)*ND0 + j];
                au0 += p0 * wu; au1 += p1 * wu;
                av0 += p0 * wv; av1 += p1 * wv;
            }
            U[bn0*ND0 + j] = au0;
            U[(bn0 + 1)*ND0 + j] = au1;
            V[bn0*ND0 + j] = av0;
            V[(bn0 + 1)*ND0 + j] = av1;
            VT_f[((size_t)b*ND0 + j)*NN + n0] = (float)av0;
            VT_f[((size_t)b*ND0 + j)*NN + n0 + 1] = (float)av1;
        }
    } else {
        // ---- proj1 role: one (b, n) ----
        int bn = bi - NB*(NN/2);
        int b = bn / NN, n = bn % NN;
        if (tid < NC) {
            int c = tid;
            double div = exp((double)(2*(c >> 1)) * (-log(10000.0) / (double)NC));
            double ang = (double)n * div;
            double pe = (c & 1) ? cos(ang) : sin(ang);
            rowf[c] = (float)((double)latent[(b*NC + c)*NN + n] + pe);
        }
        __syncthreads();
        for (int c = tid; c < NC1; c += 256) {
            float al = bl[c], ar = br[c];
            #pragma unroll 8
            for (int k = 0; k < NC; ++k) {
                float p = rowf[k];
                al += p * wl[k*NC1 + c];
                ar += p * wr[k*NC1 + c];
            }
            xl1[(size_t)bn*NC1 + c] = al;
            xr1[(size_t)bn*NC1 + c] = ar;
            xl1T[((size_t)b*NC1 + c)*256 + n] = al;
        }
    }
}

// ---------------- K3a: f32 adj MLP + gumbel margin -> WT + borderline list
__global__ void __launch_bounds__(1024)
k_adj32(const double* __restrict__ U, const float* __restrict__ VT,
        const float* __restrict__ w2, const float* __restrict__ b2,
        const float* __restrict__ gum, float* __restrict__ WT,
        int* __restrict__ blist, int* __restrict__ bcount) {
    __shared__ float Ul[TT][ND0];           // 6.4 KB
    __shared__ float w2l[ND0];              // 3.2 KB
    __shared__ float part[JC][TT][256];     // 8 KB
    int bi = blockIdx.x;
    int b = bi / (NN/TT);
    int t0 = (bi % (NN/TT)) * TT;
    int tid = threadIdx.x;
    int s = tid & 255;
    int chunk = tid >> 8;
    for (int idx = tid; idx < TT*ND0; idx += 1024) {
        int tt = idx / ND0, j = idx - tt*ND0;
        Ul[tt][j] = (float)U[((size_t)(b*NN + t0 + tt))*ND0 + j];
    }
    for (int j = tid; j < ND0; j += 1024) w2l[j] = w2[j];
    __syncthreads();
    float a0 = 0.0f, a1 = 0.0f;
    if (s < NN) {
        const float* vp = VT + ((size_t)b*ND0 + chunk*JW)*NN + s;
        int j0 = chunk*JW;
        #pragma unroll 4
        for (int jj = 0; jj < JW; ++jj) {
            float v = vp[(size_t)jj*NN];
            float w = w2l[j0 + jj];
            float h0 = Ul[0][j0 + jj] + v; h0 = (h0 >= 0.0f) ? h0 : 0.01f*h0; a0 = fmaf(h0, w, a0);
            float h1 = Ul[1][j0 + jj] + v; h1 = (h1 >= 0.0f) ? h1 : 0.01f*h1; a1 = fmaf(h1, w, a1);
        }
    }
    part[chunk][0][s] = a0;
    part[chunk][1][s] = a1;
    __syncthreads();
    if (tid < TT*NN) {
        int tt = tid / NN, ss = tid - tt*NN;
        float acc = b2[0] + part[0][tt][ss] + part[1][tt][ss]
                  + part[2][tt][ss] + part[3][tt][ss];
        int t = t0 + tt;
        float adj = 1.0f/(1.0f + expf(-acc));
        float l1 = logf(fmaxf(adj, 1e-4f));
        float l0 = logf(fmaxf(1.0f - adj, 1e-4f));
        float g0 = gum[((size_t)(b*NN + t)*NN + ss)*2 + 0];
        float g1 = gum[((size_t)(b*NN + t)*NN + ss)*2 + 1];
        float margin = (l1 + g1) - (l0 + g0);
        if (fabsf(margin) <= TH_MARGIN) {
            int li = atomicAdd(bcount, 1);
            blist[li] = (b*NN + t)*NN + ss;
        }
        WT[((size_t)(b*NN + ss))*NN + t] = (margin > 0.0f) ? adj : 0.0f;
    }
}

// ---------------- K3b: f64 exact recompute for borderline pairs (one pair per wave, wide grid)
__global__ void __launch_bounds__(256)
k_adjfix(const double* __restrict__ U, const double* __restrict__ V,
         const float* __restrict__ w2, const float* __restrict__ b2,
         const float* __restrict__ gum, const int* __restrict__ blist,
         const int* __restrict__ bcount, float* __restrict__ WT) {
    int nfix = *bcount;
    int gwid = (blockIdx.x * blockDim.x + threadIdx.x) >> 6;
    int lane = threadIdx.x & 63;
    int nw = (gridDim.x * blockDim.x) >> 6;
    for (int i = gwid; i < nfix; i += nw) {
        int code = blist[i];
        int s = code % NN;
        int t = (code / NN) % NN;
        int b = code / (NN*NN);
        const double* up = U + ((size_t)(b*NN + t))*ND0;
        const double* vp = V + ((size_t)(b*NN + s))*ND0;
        double a = 0.0;
        for (int j = lane; j < ND0; j += 64) {
            double h = up[j] + vp[j];
            h = (h >= 0.0) ? h : 0.01*h;
            a += h * (double)w2[j];
        }
        for (int off = 32; off >= 1; off >>= 1) a += __shfl_xor(a, off);
        if (lane == 0) {
            double acc = a + (double)b2[0];
            double adj = 1.0/(1.0 + exp(-acc));
            double l1 = log(fmax(adj, 1e-4));
            double l0 = log(fmax(1.0 - adj, 1e-4));
            double g0 = (double)gum[((size_t)(b*NN + t)*NN + s)*2 + 0];
            double g1 = (double)gum[((size_t)(b*NN + t)*NN + s)*2 + 1];
            double z0 = l0 + g0, z1 = l1 + g1;
            double m = fmax(z0, z1);
            double e0 = exp(z0 - m), e1 = exp(z1 - m);
            double sm = e0 + e1;
            int cg = (e1/sm) > (e0/sm);
            WT[((size_t)(b*NN + s))*NN + t] = cg ? (float)adj : 0.0f;
        }
    }
}

// ---------------- K5a: GAT1 logits + softmax -> alphaG[(b*NH+h)*NN+t][s]
__global__ void __launch_bounds__(256)
k_gat1a(const float* __restrict__ xl1T, const float* __restrict__ xr1,
        const float* __restrict__ WT, const float* __restrict__ we,
        const float* __restrict__ att, float* __restrict__ alphaG) {
    __shared__ float wred[4];
    __shared__ float mxs, sms;
    int blk = blockIdx.x;          // (b*NH + h)*NN + t
    int t = blk % NN;
    int bh = blk / NN;
    int h = bh % NH;
    int b = bh / NH;
    int s = threadIdx.x;
    int lane = s & 63, wid = s >> 6;
    float wt = (s < NN) ? WT[((size_t)(b*NN + t))*NN + s] : 0.0f;
    const float* xT  = xl1T + ((size_t)b*NC1 + h*NO1)*256;
    const float* xr  = xr1 + ((size_t)(b*NN + t))*NC1 + h*NO1;
    const float* weh = we + h*NO1;
    const float* ath = att + h*NO1;
    float a = 0.0f;
    #pragma unroll 5
    for (int o = 0; o < NO1; ++o) {
        float x = xT[(size_t)o*256 + s];
        float v = fmaf(wt, weh[o], x + xr[o]);
        float av = ath[o];
        a += fmaxf(v, 0.0f)*av + fminf(v, 0.0f)*(0.2f*av);
    }
    bool on = (s < NN) && (wt != 0.0f);
    float m = on ? a : NEGF;
    #pragma unroll
    for (int off = 32; off >= 1; off >>= 1) m = fmaxf(m, __shfl_xor(m, off));
    if (lane == 0) wred[wid] = m;
    __syncthreads();
    if (s == 0) mxs = fmaxf(fmaxf(wred[0], wred[1]), fmaxf(wred[2], wred[3]));
    __syncthreads();
    float e = on ? expf(a - mxs) : 0.0f;
    float r = e;
    #pragma unroll
    for (int off = 32; off >= 1; off >>= 1) r += __shfl_xor(r, off);
    if (lane == 0) wred[wid] = r;
    __syncthreads();
    if (s == 0) sms = wred[0] + wred[1] + wred[2] + wred[3];
    __syncthreads();
    alphaG[(size_t)blk*256 + s] = (sms > 0.0f) ? e / sms : 0.0f;
}

// ---------------- K5b: GAT1 aggregate (TQ=2 targets/block, 392 blocks)
__global__ void __launch_bounds__(640)
k_gat1b(const float* __restrict__ xl1, const float* __restrict__ alphaG,
        const float* __restrict__ bias, float* __restrict__ x1) {
    int blk = blockIdx.x;
    int b = blk / (NN/TQ), tq = blk % (NN/TQ);
    int tid = threadIdx.x;
    int w = tid >> 6, l = tid & 63;
    int h = w >> 1, csub = w & 1;
    int o = csub*64 + l;
    bool active = (o < NO1);
    int c = h*NO1 + (active ? o : 0);
    const float* ap = alphaG + (((size_t)b*NH + h)*NN + tq*TQ)*256;
    const float* xp = xl1 + (size_t)b*NN*NC1 + c;
    float a0 = 0.f, a1 = 0.f;
    for (int s = 0; s < NN; ++s) {
        float x = xp[(size_t)s*NC1];
        a0 = fmaf(ap[s], x, a0);
        a1 = fmaf(ap[256 + s], x, a1);
    }
    if (active) {
        float bs = bias[c];
        float v;
        v = a0 + bs; x1[((size_t)(b*NN + tq*TQ + 0))*NC1 + c] = (v >= 0.f) ? v : 0.01f*v;
        v = a1 + bs; x1[((size_t)(b*NN + tq*TQ + 1))*NC1 + c] = (v >= 0.f) ? v : 0.01f*v;
    }
}

// ---------------- K6: GAT2 head-0 projections
__global__ void k_proj2(const float* __restrict__ x1, const float* __restrict__ wl, const float* __restrict__ bl,
                        const float* __restrict__ wr, const float* __restrict__ br,
                        float* __restrict__ xl2, float* __restrict__ xl2T, float* __restrict__ xr2) {
    __shared__ float row[NC1];
    __shared__ float part[256];
    int bn = blockIdx.x;
    int b = bn / NN, n = bn % NN;
    int tid = threadIdx.x;
    for (int c = tid; c < NC1; c += 256) row[c] = x1[(size_t)bn*NC1 + c];
    __syncthreads();
    int which = tid >> 7;
    int o = tid & 63;
    int half = (tid >> 6) & 1;
    const float* w = which ? wr : wl;
    float acc = 0.0f;
    for (int k = half*250; k < half*250 + 250; ++k)
        acc += row[k] * w[(size_t)k*320 + o];
    part[tid] = acc;
    __syncthreads();
    if ((tid & 64) == 0) {
        float tot = part[tid] + part[tid + 64];
        if (which == 0) {
            float v = tot + bl[o];
            xl2[(size_t)bn*NO2 + o] = v;
            xl2T[((size_t)b*NO2 + o)*256 + n] = v;
        } else {
            xr2[(size_t)bn*NO2 + o] = tot + br[o];
        }
    }
}

// ---------------- K7: GAT2 head-0 attention + final channel softmax -> out
__global__ void __launch_bounds__(256)
k_gat2(const float* __restrict__ xl2T, const float* __restrict__ xl2,
       const float* __restrict__ xr2, const float* __restrict__ WT,
       const float* __restrict__ we, const float* __restrict__ att,
       const float* __restrict__ bias, float* __restrict__ out) {
    __shared__ float red[256], alpha_l[256], part[4][NO2];
    __shared__ float mxs, sms;
    int blk = blockIdx.x;
    int b = blk / NN, t = blk % NN;
    int s = threadIdx.x;
    float wt = (s < NN) ? WT[((size_t)(b*NN + t))*NN + s] : 0.0f;
    const float* xT = xl2T + (size_t)b*NO2*256;
    const float* xr = xr2 + ((size_t)(b*NN + t))*NO2;
    float acc = 0.0f;
    for (int c = 0; c < NO2; ++c) {
        float x = xT[(size_t)c*256 + s];
        float v = fmaf(wt, we[c], x + xr[c]);
        float av = att[c];
        acc += fmaxf(v, 0.0f)*av + fminf(v, 0.0f)*(0.2f*av);
    }
    bool on = (s < NN) && (wt != 0.0f);
    float lgt = on ? acc : NEGF;
    red[s] = lgt;
    __syncthreads();
    for (int d = 128; d >= 1; d >>= 1) {
        if (s < d) red[s] = fmaxf(red[s], red[s + d]);
        __syncthreads();
    }
    if (s == 0) mxs = red[0];
    __syncthreads();
    float e = on ? expf(acc - mxs) : 0.0f;
    red[s] = e;
    __syncthreads();
    for (int d = 128; d >= 1; d >>= 1) {
        if (s < d) red[s] += red[s + d];
        __syncthreads();
    }
    if (s == 0) sms = red[0];
    __syncthreads();
    alpha_l[s] = (sms > 0.0f) ? e / sms : 0.0f;
    __syncthreads();
    int c = s & 63, sq = s >> 6;
    float pa = 0.0f;
    const float* xp = xl2 + (size_t)b*NN*NO2 + c;
    for (int ss = sq*49; ss < sq*49 + 49; ++ss)
        pa = fmaf(alpha_l[ss], xp[(size_t)ss*NO2], pa);
    part[sq][c] = pa;
    __syncthreads();
    if (s < NO2) {
        float ny = part[0][s] + part[1][s] + part[2][s] + part[3][s] + bias[s];
        float m = ny;
        for (int off = 32; off >= 1; off >>= 1) m = fmaxf(m, __shfl_xor(m, off));
        float ee = expf(ny - m);
        float ssum = ee;
        for (int off = 32; off >= 1; off >>= 1) ssum += __shfl_xor(ssum, off);
        out[((size_t)(b*NN + t))*NO2 + s] = ee / ssum;
    }
}

extern "C" void kernel_launch(void* const* d_in, const int* in_sizes, int n_in,
                              void* d_out, int out_size, void* d_ws, size_t ws_size,
                              hipStream_t stream) {
    const float* latent  = (const float*)d_in[0];
    const float* gum     = (const float*)d_in[1];
    const float* d0_w1   = (const float*)d_in[2];
    const float* d0_b1   = (const float*)d_in[3];
    const float* d0_w2   = (const float*)d_in[4];
    const float* d0_b2   = (const float*)d_in[5];
    const float* g1_wl   = (const float*)d_in[12];
    const float* g1_bl   = (const float*)d_in[13];
    const float* g1_wr   = (const float*)d_in[14];
    const float* g1_br   = (const float*)d_in[15];
    const float* g1_we   = (const float*)d_in[16];
    const float* g1_att  = (const float*)d_in[17];
    const float* g1_bias = (const float*)d_in[18];
    const float* g2_wl   = (const float*)d_in[19];
    const float* g2_bl   = (const float*)d_in[20];
    const float* g2_wr   = (const float*)d_in[21];
    const float* g2_br   = (const float*)d_in[22];
    const float* g2_we   = (const float*)d_in[23];
    const float* g2_att  = (const float*)d_in[24];
    const float* g2_bias = (const float*)d_in[25];
    float* out = (float*)d_out;

    char* ws = (char*)d_ws;
    size_t off = 0;
    auto alloc = [&](size_t bytes) { char* p = ws + off; off += (bytes + 255) & ~(size_t)255; return (void*)p; };
    double* U_d   = (double*)alloc((size_t)NB*NN*ND0*8);
    double* V_d   = (double*)alloc((size_t)NB*NN*ND0*8);
    float*  VT_f  = (float*) alloc((size_t)NB*ND0*NN*4);
    float*  WT    = (float*) alloc((size_t)NB*NN*NN*4);
    float*  xl1   = (float*) alloc((size_t)NB*NN*NC1*4);
    float*  xl1T  = (float*) alloc((size_t)NB*NC1*256*4);
    float*  xr1   = (float*) alloc((size_t)NB*NN*NC1*4);
    float*  alphaG= (float*) alloc((size_t)NB*NH*NN*256*4);
    float*  x1    = (float*) alloc((size_t)NB*NN*NC1*4);
    float*  xl2   = (float*) alloc((size_t)NB*NN*NO2*4);
    float*  xl2T  = (float*) alloc((size_t)NB*NO2*256*4);
    float*  xr2   = (float*) alloc((size_t)NB*NN*NO2*4);
    int*    blist = (int*)   alloc((size_t)NB*NN*NN*4);
    int*    bcount= (int*)   alloc(256);

    hipLaunchKernelGGL(k_head,   dim3(NB*(NN/2) + NB*NN), dim3(256), 0, stream,
                       latent, d0_w1, d0_b1, g1_wl, g1_bl, g1_wr, g1_br,
                       U_d, V_d, VT_f, xl1, xl1T, xr1, bcount);
    hipLaunchKernelGGL(k_adj32,  dim3(NB*(NN/TT)),  dim3(1024), 0, stream, U_d, VT_f, d0_w2, d0_b2, gum, WT, blist, bcount);
    hipLaunchKernelGGL(k_adjfix, dim3(256),         dim3(256),  0, stream, U_d, V_d, d0_w2, d0_b2, gum, blist, bcount, WT);
    hipLaunchKernelGGL(k_gat1a,  dim3(NB*NH*NN),    dim3(256),  0, stream, xl1T, xr1, WT, g1_we, g1_att, alphaG);
    hipLaunchKernelGGL(k_gat1b,  dim3(NB*(NN/TQ)),  dim3(640),  0, stream, xl1, alphaG, g1_bias, x1);
    hipLaunchKernelGGL(k_proj2,  dim3(NB*NN),       dim3(256),  0, stream, x1, g2_wl, g2_bl, g2_wr, g2_br, xl2, xl2T, xr2);
    hipLaunchKernelGGL(k_gat2,   dim3(NB*NN),       dim3(256),  0, stream, xl2T, xl2, xr2, WT, g2_we, g2_att, g2_bias, out);
}